// Round 15
// baseline (485.978 us; speedup 1.0000x reference)
//
#include <hip/hip_runtime.h>
#include <hip/hip_fp8.h>
#include <math.h>

typedef __attribute__((ext_vector_type(8))) short short8v;   // 8 x bf16 (4 VGPRs)
typedef __attribute__((ext_vector_type(4))) float f32x4;
typedef __attribute__((ext_vector_type(2))) float f32x2;

__device__ __forceinline__ float bf2f(unsigned short u) {
    union { unsigned int i; float f; } x; x.i = ((unsigned int)u) << 16; return x.f;
}
__device__ __forceinline__ unsigned short f2bf(float f) {
    union { float f; unsigned int i; } x; x.f = f;
    unsigned int r = x.i + 0x7fffu + ((x.i >> 16) & 1u);
    return (unsigned short)(r >> 16);
}
// HW packed f32x2 -> 2 x bf16 (v_cvt_pk_bf16_f32, RTNE)
__device__ __forceinline__ unsigned int pk_bf16(float lo, float hi) {
    unsigned int r;
    asm("v_cvt_pk_bf16_f32 %0, %1, %2" : "=v"(r) : "v"(lo), "v"(hi));
    return r;
}
// HW packed 4 x f32 -> 4 x fp8 e4m3 (two v_cvt_pk_fp8_f32)
__device__ __forceinline__ unsigned int pk_fp8x4(float v0, float v1, float v2, float v3) {
    int pk = __builtin_amdgcn_cvt_pk_fp8_f32(v0, v1, 0, false);
    pk = __builtin_amdgcn_cvt_pk_fp8_f32(v2, v3, pk, true);
    return (unsigned int)pk;
}
// tanh-form gelu (~10 ops)
__device__ __forceinline__ float gelu_fast(float x) {
    float y = 0.7978845608f * x * fmaf(0.044715f, x * x, 1.0f);
    y = fminf(fmaxf(y, -9.f), 9.f);
    float u = exp2f(y * 2.8853900817779268f);   // e^{2y}
    float th = 1.f - 2.f * __builtin_amdgcn_rcpf(u + 1.f);
    return 0.5f * x * (1.f + th);
}

// ============ bf16 MFMA GEMM body; B direct from global (L2-hot) ============
template <int K, int MODE, int ASRC>
__device__ __forceinline__ void gemm_body(
    const void* __restrict__ Aptr, const unsigned short* __restrict__ BT,
    const float* __restrict__ bias, unsigned short* __restrict__ Cout, int M,
    const unsigned short* __restrict__ hprev, const float* __restrict__ skipp, int blk) {
    __shared__ short As[128 * K];
    const int tid = threadIdx.x;
    const int row0 = blk * 128;
    const int CH = K / 8;

#pragma unroll
    for (int i = 0; i < (128 * CH) / 256; ++i) {
        int idx = tid + i * 256;
        int r = idx / CH, c = idx % CH;
        int gr = row0 + r;
        if (ASRC == 0) {
            short8v val = {0, 0, 0, 0, 0, 0, 0, 0};
            if (gr < M)
                val = *reinterpret_cast<const short8v*>(
                    (const unsigned short*)Aptr + (size_t)gr * K + c * 8);
            if (MODE == 2) {
                float fv[8];
#pragma unroll
                for (int u = 0; u < 8; ++u) fv[u] = gelu_fast(bf2f((unsigned short)val[u]));
                uint4 uu;
                uu.x = pk_bf16(fv[0], fv[1]);
                uu.y = pk_bf16(fv[2], fv[3]);
                uu.z = pk_bf16(fv[4], fv[5]);
                uu.w = pk_bf16(fv[6], fv[7]);
                *reinterpret_cast<uint4*>((char*)As + r * (2 * K) +
                                          ((c * 16) ^ ((r & 7) << 4))) = uu;
            } else {
                *reinterpret_cast<short8v*>((char*)As + r * (2 * K) +
                                            ((c * 16) ^ ((r & 7) << 4))) = val;
            }
        } else {
            uint4 u = make_uint4(0u, 0u, 0u, 0u);
            if (gr < M) {
                const float* Af = (const float*)Aptr;
                float4 f0 = *reinterpret_cast<const float4*>(Af + (size_t)gr * K + c * 8);
                float4 f1 = *reinterpret_cast<const float4*>(Af + (size_t)gr * K + c * 8 + 4);
                if (MODE == 2) {
                    f0.x = gelu_fast(f0.x); f0.y = gelu_fast(f0.y);
                    f0.z = gelu_fast(f0.z); f0.w = gelu_fast(f0.w);
                    f1.x = gelu_fast(f1.x); f1.y = gelu_fast(f1.y);
                    f1.z = gelu_fast(f1.z); f1.w = gelu_fast(f1.w);
                }
                u.x = pk_bf16(f0.x, f0.y);
                u.y = pk_bf16(f0.z, f0.w);
                u.z = pk_bf16(f1.x, f1.y);
                u.w = pk_bf16(f1.z, f1.w);
            }
            *reinterpret_cast<uint4*>((char*)As + r * (2 * K) + ((c * 16) ^ ((r & 7) << 4))) = u;
        }
    }
    __syncthreads();

    const int lane = tid & 63, wid = tid >> 6;
    const int wr = wid >> 1, wc = wid & 1;
    const int lr = lane & 15, lg = lane >> 4;
    const int swz = (lr & 7) << 4;
    const unsigned short* bbase = BT + (size_t)(wc * 64 + lr) * K + lg * 8;
    f32x4 acc[4][4];
    f32x4 z4 = {0.f, 0.f, 0.f, 0.f};
#pragma unroll
    for (int mi = 0; mi < 4; ++mi)
#pragma unroll
        for (int ni = 0; ni < 4; ++ni) acc[mi][ni] = z4;

#pragma unroll
    for (int ks = 0; ks < K / 32; ++ks) {
        int kc = ks * 64 + lg * 16;
        short8v a[4], b[4];
#pragma unroll
        for (int ni = 0; ni < 4; ++ni)
            b[ni] = *reinterpret_cast<const short8v*>(bbase + (size_t)ni * 16 * K + ks * 32);
#pragma unroll
        for (int mi = 0; mi < 4; ++mi) {
            int r = wr * 64 + mi * 16 + lr;
            a[mi] = *reinterpret_cast<const short8v*>((char*)As + r * (2 * K) + (kc ^ swz));
        }
#pragma unroll
        for (int mi = 0; mi < 4; ++mi)
#pragma unroll
            for (int ni = 0; ni < 4; ++ni)
                acc[mi][ni] =
                    __builtin_amdgcn_mfma_f32_16x16x32_bf16(b[ni], a[mi], acc[mi][ni], 0, 0, 0);
    }

    float beta = 0.f;
    if (MODE == 2) beta = 1.f / (1.f + __expf(-skipp[0]));
#pragma unroll
    for (int mi = 0; mi < 4; ++mi) {
        int gr = row0 + wr * 64 + mi * 16 + lr;
        if (gr >= M) continue;
#pragma unroll
        for (int ni = 0; ni < 4; ++ni) {
            int col0 = wc * 64 + ni * 16 + lg * 4;
            float4 bv = *reinterpret_cast<const float4*>(bias + col0);
            float v0 = acc[mi][ni][0] + bv.x;
            float v1 = acc[mi][ni][1] + bv.y;
            float v2 = acc[mi][ni][2] + bv.z;
            float v3 = acc[mi][ni][3] + bv.w;
            if (MODE == 1) {
                v0 = fmaxf(v0, 0.f); v1 = fmaxf(v1, 0.f);
                v2 = fmaxf(v2, 0.f); v3 = fmaxf(v3, 0.f);
            }
            if (MODE == 2) {
                ushort4 hp = *reinterpret_cast<const ushort4*>(hprev + (size_t)gr * 128 + col0);
                float ob = 1.f - beta;
                v0 = beta * v0 + ob * bf2f(hp.x);
                v1 = beta * v1 + ob * bf2f(hp.y);
                v2 = beta * v2 + ob * bf2f(hp.z);
                v3 = beta * v3 + ob * bf2f(hp.w);
            }
            uint2 us;
            us.x = pk_bf16(v0, v1);
            us.y = pk_bf16(v2, v3);
            *reinterpret_cast<uint2*>(Cout + (size_t)gr * 128 + col0) = us;
        }
    }
}

template <int K, int MODE, int ASRC>
__global__ __launch_bounds__(256) void gemm_dual(
    const void* A0, const unsigned short* BT0, const float* b0, unsigned short* C0, int M0,
    const unsigned short* hp0, const float* sk0,
    const void* A1, const unsigned short* BT1, const float* b1, unsigned short* C1, int M1,
    const unsigned short* hp1, const float* sk1, int nb0) {
    if ((int)blockIdx.x < nb0)
        gemm_body<K, MODE, ASRC>(A0, BT0, b0, C0, M0, hp0, sk0, blockIdx.x);
    else
        gemm_body<K, MODE, ASRC>(A1, BT1, b1, C1, M1, hp1, sk1, blockIdx.x - nb0);
}

// ============ fused QKV GEMM: A direct global->reg (no LDS, no barrier) ============
struct QKVJobs {
    const unsigned short* BT[5];
    const float* bias[5];
    unsigned short* outBf[5];
    unsigned char* outF8[5];
    int f8off[5];   // 0 for K, 128 for V
};

template <int NB>
__device__ __forceinline__ void qkv_body(const unsigned short* __restrict__ A,
                                         const QKVJobs& J, int M, int blk) {
    const int tid = threadIdx.x;
    const int row0 = blk * 128;
    const int lane = tid & 63, wid = tid >> 6;
    const int wr = wid >> 1, wc = wid & 1;
    const int lr = lane & 15, lg = lane >> 4;

    // A fragments loaded ONCE per block directly from global (L2-hot),
    // reused across all NB jobs. Rows beyond M -> zero.
    short8v a[4][4];   // [ks][mi]
#pragma unroll
    for (int mi = 0; mi < 4; ++mi) {
        int gr = row0 + wr * 64 + mi * 16 + lr;
        bool ok = gr < M;
        const unsigned short* arow = A + (size_t)gr * 128 + lg * 8;
#pragma unroll
        for (int ks = 0; ks < 4; ++ks) {
            short8v z = {0, 0, 0, 0, 0, 0, 0, 0};
            a[ks][mi] = ok ? *reinterpret_cast<const short8v*>(arow + ks * 32) : z;
        }
    }

#pragma unroll
    for (int m = 0; m < NB; ++m) {
        const unsigned short* bbase = J.BT[m] + (size_t)(wc * 64 + lr) * 128 + lg * 8;
        f32x4 acc[4][4];
        f32x4 z4 = {0.f, 0.f, 0.f, 0.f};
#pragma unroll
        for (int mi = 0; mi < 4; ++mi)
#pragma unroll
            for (int ni = 0; ni < 4; ++ni) acc[mi][ni] = z4;

#pragma unroll
        for (int ks = 0; ks < 4; ++ks) {
            short8v b[4];
#pragma unroll
            for (int ni = 0; ni < 4; ++ni)
                b[ni] = *reinterpret_cast<const short8v*>(bbase + (size_t)ni * 16 * 128 + ks * 32);
#pragma unroll
            for (int mi = 0; mi < 4; ++mi)
#pragma unroll
                for (int ni = 0; ni < 4; ++ni)
                    acc[mi][ni] = __builtin_amdgcn_mfma_f32_16x16x32_bf16(b[ni], a[ks][mi],
                                                                          acc[mi][ni], 0, 0, 0);
        }

        unsigned short* outBf = J.outBf[m];
        unsigned char* outF8 = J.outF8[m];
        int off = J.f8off[m];
        const float* bias = J.bias[m];
#pragma unroll
        for (int mi = 0; mi < 4; ++mi) {
            int gr = row0 + wr * 64 + mi * 16 + lr;
            if (gr >= M) continue;
#pragma unroll
            for (int ni = 0; ni < 4; ++ni) {
                int col0 = wc * 64 + ni * 16 + lg * 4;
                float4 bv = *reinterpret_cast<const float4*>(bias + col0);
                float v0 = acc[mi][ni][0] + bv.x;
                float v1 = acc[mi][ni][1] + bv.y;
                float v2 = acc[mi][ni][2] + bv.z;
                float v3 = acc[mi][ni][3] + bv.w;
                if (outBf) {
                    uint2 us;
                    us.x = pk_bf16(v0, v1);
                    us.y = pk_bf16(v2, v3);
                    *reinterpret_cast<uint2*>(outBf + (size_t)gr * 128 + col0) = us;
                } else {
                    *reinterpret_cast<unsigned int*>(outF8 + (size_t)gr * 256 + off + col0) =
                        pk_fp8x4(v0, v1, v2, v3);
                }
            }
        }
    }
}

__global__ __launch_bounds__(256) void gemm_qkv2(const unsigned short* A0, QKVJobs J0, int M0,
                                                 int nb0, const unsigned short* A1,
                                                 QKVJobs J1, int M1) {
    if ((int)blockIdx.x < nb0) qkv_body<5>(A0, J0, M0, blockIdx.x);
    else qkv_body<3>(A1, J1, M1, blockIdx.x - nb0);
}

// ============ weight prep ============
__global__ void convT_kernel(const float* __restrict__ Win0, const float* __restrict__ Win1,
                             const float* __restrict__ Wq, const float* __restrict__ Wa,
                             unsigned short* __restrict__ winT, unsigned short* __restrict__ wqT,
                             unsigned short* __restrict__ waT, int nmat) {
    int gid = blockIdx.x * 256 + threadIdx.x;
    if (gid < 2 * 8192) {
        int m = gid >> 13, idx = gid & 8191;
        int n = idx >> 6, k = idx & 63;
        const float* W = m ? Win1 : Win0;
        winT[gid] = f2bf(W[(size_t)k * 128 + n]);
        return;
    }
    int g = gid - 2 * 8192;
    if (g < nmat * 16384) {
        int mat = g >> 14, idx = g & 16383;
        int n = idx >> 7, k = idx & 127;
        wqT[g] = f2bf(Wq[(size_t)mat * 16384 + (size_t)k * 128 + n]);
        return;
    }
    g -= nmat * 16384;
    if (g < nmat * 16384) {
        int mat = g >> 14, idx = g & 16383;
        int n = idx >> 7, k = idx & 127;
        waT[g] = f2bf(Wa[(size_t)mat * 16384 + (size_t)k * 128 + n]);
    }
}

// ============ relation fold ============
__global__ void fold_kernel(const float* __restrict__ Wk, const float* __restrict__ bk,
                            const float* __restrict__ Wv, const float* __restrict__ bv,
                            const float* __restrict__ a_rel, const float* __restrict__ m_rel,
                            unsigned short* __restrict__ wfT, float* __restrict__ bfold, int L) {
    const int RSarr[3] = {0, 1, 0};
    int gid = blockIdx.x * 256 + threadIdx.x;
    int NW = L * 6 * 16384;
    if (gid < NW) {
        int fold = gid >> 14, idx = gid & 16383;
        int col = idx >> 7, i = idx & 127;
        int kv = fold & 1, lr = fold >> 1, l = lr / 3, r = lr % 3;
        int s = RSarr[r];
        const float* W = (kv ? Wv : Wk) + (size_t)(l * 2 + s) * 16384;
        const float* rel = (kv ? m_rel : a_rel) + (size_t)(l * 3 + r) * 2048;
        int hh = col >> 4, f = col & 15;
        float sacc = 0.f;
#pragma unroll
        for (int d = 0; d < 16; ++d)
            sacc += W[(size_t)i * 128 + hh * 16 + d] * rel[hh * 256 + d * 16 + f];
        wfT[gid] = f2bf(sacc);
        return;
    }
    int g = gid - NW;
    if (g >= L * 6 * 128) return;
    int fold = g >> 7, col = g & 127;
    int kv = fold & 1, lr = fold >> 1, l = lr / 3, r = lr % 3;
    int s = RSarr[r];
    const float* b = (kv ? bv : bk) + (size_t)(l * 2 + s) * 128;
    const float* rel = (kv ? m_rel : a_rel) + (size_t)(l * 3 + r) * 2048;
    int hh = col >> 4, f = col & 15;
    float sacc = 0.f;
#pragma unroll
    for (int d = 0; d < 16; ++d) sacc += b[hh * 16 + d] * rel[hh * 256 + d * 16 + f];
    bfold[fold * 128 + col] = sacc;
}

// ============ CSR build ============
struct Csr3 {
    const int* src[3];
    const int* dst[3];
    int E[3];
    int* cnt;
    int* texcl;
    int* bsums;
    int* indptr[3];
    int* ssrc[3];
    int Nd[3];
    int nb[3];
    int stride;
};

// ---- fallback path (generic N) ----
__global__ void hist3_kernel(Csr3 P, int Etot) {
    int gid = blockIdx.x * 256 + threadIdx.x;
    if (gid >= Etot) return;
    int r = 0, off = gid;
    if (off >= P.E[0]) { off -= P.E[0]; r = 1; if (off >= P.E[1]) { off -= P.E[1]; r = 2; } }
    atomicAdd(&P.cnt[r * P.stride + P.dst[r][off]], 1);
}

__global__ __launch_bounds__(1024) void scanA3_kernel(Csr3 P) {
    __shared__ int s[1024];
    int b = blockIdx.x, r = 0;
    while (b >= P.nb[r]) { b -= P.nb[r]; ++r; }
    const int* cnt = P.cnt + r * P.stride;
    int* texcl = P.texcl + r * P.stride;
    int n = P.Nd[r];
    int t = threadIdx.x;
    int gid = b * 1024 + t;
    int x = (gid < n) ? cnt[gid] : 0;
    s[t] = x;
    __syncthreads();
    for (int off = 1; off < 1024; off <<= 1) {
        int v = (t >= off) ? s[t - off] : 0;
        __syncthreads();
        s[t] += v;
        __syncthreads();
    }
    if (gid < n) texcl[gid] = s[t] - x;
    if (t == 1023) P.bsums[r * 64 + b] = s[1023];
}

__global__ void scanB3_kernel(Csr3 P) {
    int r = blockIdx.x;
    if (threadIdx.x == 0) {
        int run = 0;
        for (int i = 0; i < P.nb[r]; ++i) {
            int t = P.bsums[r * 64 + i];
            P.bsums[r * 64 + i] = run;
            run += t;
        }
    }
}

__global__ __launch_bounds__(1024) void scanC3_kernel(Csr3 P) {
    int b = blockIdx.x, r = 0;
    while (b >= P.nb[r]) { b -= P.nb[r]; ++r; }
    int n = P.Nd[r];
    int gid = b * 1024 + threadIdx.x;
    if (gid < n) {
        int v = P.texcl[r * P.stride + gid] + P.bsums[r * 64 + b];
        P.indptr[r][gid] = v;
        P.cnt[r * P.stride + gid] = v;
    }
    if (gid == 0) P.indptr[r][n] = P.E[r];
}

__global__ void scatter3_kernel(Csr3 P, int Etot) {
    int gid = blockIdx.x * 256 + threadIdx.x;
    if (gid >= Etot) return;
    int r = 0, off = gid;
    if (off >= P.E[0]) { off -= P.E[0]; r = 1; if (off >= P.E[1]) { off -= P.E[1]; r = 2; } }
    int d = P.dst[r][off];
    int p = atomicAdd(&P.cnt[r * P.stride + d], 1);
    P.ssrc[r][p] = P.src[r][off];
}

// ---- fast path (N<=65536): bucket-local CSR ----
#define CA_TILE 4096
__global__ __launch_bounds__(256) void countA_kernel(Csr3 P, int* __restrict__ gbkt) {
    const int r = blockIdx.x >> 6;
    const int blk = blockIdx.x & 63;
    const int tid = threadIdx.x;
    const int* __restrict__ dstp = P.dst[r];
    const int E = P.E[r];
    __shared__ int lc[64];
    for (int t0 = blk * CA_TILE; t0 < E; t0 += 64 * CA_TILE) {
        int cnt = E - t0;
        if (cnt > CA_TILE) cnt = CA_TILE;
        if (tid < 64) lc[tid] = 0;
        __syncthreads();
        for (int i = tid; i < cnt; i += 256) atomicAdd(&lc[dstp[t0 + i] >> 10], 1);
        __syncthreads();
        if (tid < 64 && lc[tid] > 0) atomicAdd(&gbkt[r * 65 + tid], lc[tid]);
        __syncthreads();
    }
}

__global__ void scanG_kernel(int* __restrict__ gbkt, int* __restrict__ gcur) {
    if (threadIdx.x == 0) {
        for (int r = 0; r < 3; ++r) {
            int run = 0;
            for (int b = 0; b < 64; ++b) {
                int t = gbkt[r * 65 + b];
                gbkt[r * 65 + b] = run;
                gcur[r * 64 + b] = run;
                run += t;
            }
            gbkt[r * 65 + 64] = run;
        }
    }
}

#define PA_TILE 4096
#define PA_BLKS 64
__global__ __launch_bounds__(256) void partA_kernel(Csr3 P, unsigned int* __restrict__ pb0,
                                                    unsigned int* __restrict__ pb1,
                                                    unsigned int* __restrict__ pb2,
                                                    int* __restrict__ gcur) {
    unsigned int* pbuf[3] = {pb0, pb1, pb2};
    const int r = blockIdx.x / PA_BLKS;
    const int blk = blockIdx.x % PA_BLKS;
    const int tid = threadIdx.x;
    const int* __restrict__ srcp = P.src[r];
    const int* __restrict__ dstp = P.dst[r];
    const int E = P.E[r];
    unsigned int* __restrict__ out = pbuf[r];
    __shared__ unsigned int stage[PA_TILE];
    __shared__ unsigned char bkt[PA_TILE];
    __shared__ int lcnt[64], lofs[64], lbase[64];

    for (int t0 = blk * PA_TILE; t0 < E; t0 += PA_BLKS * PA_TILE) {
        int cnt = E - t0;
        if (cnt > PA_TILE) cnt = PA_TILE;
        if (tid < 64) lcnt[tid] = 0;
        __syncthreads();
        unsigned int pk[16];
        int lp[16];
#pragma unroll
        for (int j = 0; j < 16; ++j) {
            int i = tid + j * 256;
            if (i < cnt) {
                int s = srcp[t0 + i];
                int d = dstp[t0 + i];
                pk[j] = ((unsigned int)d << 16) | (unsigned int)s;
                lp[j] = atomicAdd(&lcnt[d >> 10], 1);
            }
        }
        __syncthreads();
        if (tid == 0) {
            int run = 0;
            for (int b = 0; b < 64; ++b) { lofs[b] = run; run += lcnt[b]; }
        }
        __syncthreads();
        if (tid < 64 && lcnt[tid] > 0) lbase[tid] = atomicAdd(&gcur[r * 64 + tid], lcnt[tid]);
        __syncthreads();
#pragma unroll
        for (int j = 0; j < 16; ++j) {
            int i = tid + j * 256;
            if (i < cnt) {
                int b = pk[j] >> 26;
                int sp = lofs[b] + lp[j];
                stage[sp] = pk[j];
                bkt[sp] = (unsigned char)b;
            }
        }
        __syncthreads();
        for (int k = tid; k < cnt; k += 256) {
            int b = bkt[k];
            out[lbase[b] + (k - lofs[b])] = stage[k];
        }
        __syncthreads();
    }
}

__global__ __launch_bounds__(256) void partB2_kernel(Csr3 P, const unsigned int* __restrict__ pb0,
                                                     const unsigned int* __restrict__ pb1,
                                                     const unsigned int* __restrict__ pb2,
                                                     const int* __restrict__ gbkt) {
    const unsigned int* pbuf[3] = {pb0, pb1, pb2};
    int r = blockIdx.x >> 6, b = blockIdx.x & 63;
    int Nd = P.Nd[r];
    int nbk = (Nd + 1023) >> 10;
    if (b >= nbk) return;
    int d0 = b << 10;
    int d1 = d0 + 1024;
    if (d1 > Nd) d1 = Nd;
    int lo = gbkt[r * 65 + b];
    int hi = gbkt[r * 65 + b + 1];
    const unsigned int* __restrict__ pin = pbuf[r];
    int* __restrict__ indptr = P.indptr[r];
    int* __restrict__ out = P.ssrc[r];
    const int tid = threadIdx.x;
    __shared__ int cnt[1024];
    __shared__ int exc[1024];
    __shared__ int ps[256];

    for (int i = tid; i < 1024; i += 256) cnt[i] = 0;
    __syncthreads();
    for (int i = lo + tid; i < hi; i += 256)
        atomicAdd(&cnt[(pin[i] >> 16) & 1023], 1);
    __syncthreads();
    int base = tid * 4;
    int s0 = cnt[base], s1 = cnt[base + 1], s2 = cnt[base + 2], s3 = cnt[base + 3];
    int tsum = s0 + s1 + s2 + s3;
    ps[tid] = tsum;
    __syncthreads();
    for (int off = 1; off < 256; off <<= 1) {
        int v = (tid >= off) ? ps[tid - off] : 0;
        __syncthreads();
        ps[tid] += v;
        __syncthreads();
    }
    int texc = ps[tid] - tsum;
    exc[base] = texc;
    exc[base + 1] = texc + s0;
    exc[base + 2] = texc + s0 + s1;
    exc[base + 3] = texc + s0 + s1 + s2;
    __syncthreads();
    for (int i = tid; i < (d1 - d0); i += 256) indptr[d0 + i] = lo + exc[i];
    if (b == nbk - 1 && tid == 0) indptr[Nd] = P.E[r];
    for (int i = tid; i < 1024; i += 256) cnt[i] = exc[i];
    __syncthreads();
    for (int i = lo + tid; i < hi; i += 256) {
        unsigned int pk = pin[i];
        int dl = (pk >> 16) & 1023;
        int p = atomicAdd(&cnt[dl], 1);
        out[lo + p] = (int)(pk & 0xffffu);
    }
}

// ============ attention: head-per-lane, 4 edges/iter, planar fp8 kv, bf16 agg ============
__device__ __forceinline__ void proc4(uint4 Kw, uint4 Vw, const float qf[16], float ps,
                                      bool valid, float& ssum, float acc[16]) {
    float kx[16];
    {
        f32x2 p0 = __builtin_amdgcn_cvt_pk_f32_fp8(Kw.x, false);
        f32x2 p1 = __builtin_amdgcn_cvt_pk_f32_fp8(Kw.x, true);
        f32x2 p2 = __builtin_amdgcn_cvt_pk_f32_fp8(Kw.y, false);
        f32x2 p3 = __builtin_amdgcn_cvt_pk_f32_fp8(Kw.y, true);
        f32x2 p4 = __builtin_amdgcn_cvt_pk_f32_fp8(Kw.z, false);
        f32x2 p5 = __builtin_amdgcn_cvt_pk_f32_fp8(Kw.z, true);
        f32x2 p6 = __builtin_amdgcn_cvt_pk_f32_fp8(Kw.w, false);
        f32x2 p7 = __builtin_amdgcn_cvt_pk_f32_fp8(Kw.w, true);
        kx[0] = p0[0]; kx[1] = p0[1]; kx[2] = p1[0]; kx[3] = p1[1];
        kx[4] = p2[0]; kx[5] = p2[1]; kx[6] = p3[0]; kx[7] = p3[1];
        kx[8] = p4[0]; kx[9] = p4[1]; kx[10] = p5[0]; kx[11] = p5[1];
        kx[12] = p6[0]; kx[13] = p6[1]; kx[14] = p7[0]; kx[15] = p7[1];
    }
    float t = 0.f;
#pragma unroll
    for (int j = 0; j < 16; ++j) t = fmaf(qf[j], kx[j], t);
    float e = fminf(fmaxf(t * ps, -40.f), 40.f);
    float w = valid ? exp2f(e) : 0.f;
    ssum += w;
    float vx[16];
    {
        f32x2 p0 = __builtin_amdgcn_cvt_pk_f32_fp8(Vw.x, false);
        f32x2 p1 = __builtin_amdgcn_cvt_pk_f32_fp8(Vw.x, true);
        f32x2 p2 = __builtin_amdgcn_cvt_pk_f32_fp8(Vw.y, false);
        f32x2 p3 = __builtin_amdgcn_cvt_pk_f32_fp8(Vw.y, true);
        f32x2 p4 = __builtin_amdgcn_cvt_pk_f32_fp8(Vw.z, false);
        f32x2 p5 = __builtin_amdgcn_cvt_pk_f32_fp8(Vw.z, true);
        f32x2 p6 = __builtin_amdgcn_cvt_pk_f32_fp8(Vw.w, false);
        f32x2 p7 = __builtin_amdgcn_cvt_pk_f32_fp8(Vw.w, true);
        vx[0] = p0[0]; vx[1] = p0[1]; vx[2] = p1[0]; vx[3] = p1[1];
        vx[4] = p2[0]; vx[5] = p2[1]; vx[6] = p3[0]; vx[7] = p3[1];
        vx[8] = p4[0]; vx[9] = p4[1]; vx[10] = p5[0]; vx[11] = p5[1];
        vx[12] = p6[0]; vx[13] = p6[1]; vx[14] = p7[0]; vx[15] = p7[1];
    }
#pragma unroll
    for (int j = 0; j < 16; ++j) acc[j] = fmaf(w, vx[j], acc[j]);
}

__device__ __forceinline__ void slot_load(const unsigned char* __restrict__ kv,
                                          const int* __restrict__ ss, int beg, int n, int j4,
                                          int lq, int lhb, int eslot, int hoff, int& bat,
                                          uint4& Kw, uint4& Vw) {
    if ((j4 & 31) == 0) bat = (j4 + lq < n) ? ss[beg + j4 + lq] : 0;
    int s = __shfl(bat, lhb + ((j4 + eslot) & 31));
    const unsigned char* bp = kv + (size_t)s * 256 + hoff;
    Kw = *reinterpret_cast<const uint4*>(bp);
    Vw = *reinterpret_cast<const uint4*>(bp + 128);
}

__global__ __launch_bounds__(256) void attn_fused(
    const unsigned short* __restrict__ q0, const unsigned short* __restrict__ q1,
    const unsigned char* __restrict__ kvA, const unsigned char* __restrict__ kvB,
    const unsigned char* __restrict__ kvC,
    const int* __restrict__ ipA, const int* __restrict__ ssA,
    const int* __restrict__ ipB, const int* __restrict__ ssB,
    const int* __restrict__ ipC, const int* __restrict__ ssC,
    unsigned short* __restrict__ agg0, unsigned short* __restrict__ agg1,
    const float* __restrict__ prA, const float* __restrict__ prB,
    const float* __restrict__ prC, int N0, int N1) {
    const int wave = (blockIdx.x * blockDim.x + threadIdx.x) >> 6;
    const int lane = threadIdx.x & 63;
    const int lq = lane & 31;
    const int lhb = lane & 32;
    const int h = lq & 7;
    const int eslot = lq >> 3;
    const int hoff = h * 16;
    const float LOG2E = 1.4426950408889634f;
    const int P0 = (N0 + 1) >> 1;
    const int P1 = (N1 + 1) >> 1;
    if (wave >= P0 + P1) return;

    if (wave < P0) {
        int dst = wave * 2 + (lhb >> 5);
        bool act = dst < N0;
        float qf[16];
        int b1 = 0, n1 = 0, b2 = 0, n2 = 0;
        if (act) {
            short8v qv0 = *reinterpret_cast<const short8v*>(q0 + (size_t)dst * 128 + hoff);
            short8v qv1 = *reinterpret_cast<const short8v*>(q0 + (size_t)dst * 128 + hoff + 8);
#pragma unroll
            for (int j = 0; j < 8; ++j) {
                qf[j] = bf2f((unsigned short)qv0[j]);
                qf[8 + j] = bf2f((unsigned short)qv1[j]);
            }
            b1 = ipA[dst]; n1 = ipA[dst + 1] - b1;
            b2 = ipB[dst]; n2 = ipB[dst + 1] - b2;
        } else {
#pragma unroll
            for (int j = 0; j < 16; ++j) qf[j] = 0.f;
        }
        float ps1 = prA[h] * 0.25f * LOG2E;
        float ps2 = prB[h] * 0.25f * LOG2E;
        float ssum1 = 0.f, ssum2 = 0.f;
        float acc1[16], acc2[16];
#pragma unroll
        for (int j = 0; j < 16; ++j) { acc1[j] = 0.f; acc2[j] = 0.f; }
        int it1 = (n1 + 3) >> 2, it2 = (n2 + 3) >> 2;
        int itm = (it1 > it2) ? it1 : it2;
        int bat1 = 0, bat2 = 0;
        uint4 cK1{}, cV1{}, cK2{}, cV2{};
        if (it1 > 0) slot_load(kvA, ssA, b1, n1, 0, lq, lhb, eslot, hoff, bat1, cK1, cV1);
        if (it2 > 0) slot_load(kvB, ssB, b2, n2, 0, lq, lhb, eslot, hoff, bat2, cK2, cV2);
        for (int i = 0; i < itm; ++i) {
            uint4 nK1{}, nV1{}, nK2{}, nV2{};
            if (i + 1 < it1)
                slot_load(kvA, ssA, b1, n1, (i + 1) * 4, lq, lhb, eslot, hoff, bat1, nK1, nV1);
            if (i + 1 < it2)
                slot_load(kvB, ssB, b2, n2, (i + 1) * 4, lq, lhb, eslot, hoff, bat2, nK2, nV2);
            if (i < it1) proc4(cK1, cV1, qf, ps1, (i * 4 + eslot) < n1, ssum1, acc1);
            if (i < it2) proc4(cK2, cV2, qf, ps2, (i * 4 + eslot) < n2, ssum2, acc2);
            cK1 = nK1; cV1 = nV1; cK2 = nK2; cV2 = nV2;
        }
#pragma unroll
        for (int j = 0; j < 16; ++j) {
            acc1[j] += __shfl_xor(acc1[j], 8);
            acc1[j] += __shfl_xor(acc1[j], 16);
            acc2[j] += __shfl_xor(acc2[j], 8);
            acc2[j] += __shfl_xor(acc2[j], 16);
        }
        ssum1 += __shfl_xor(ssum1, 8);
        ssum1 += __shfl_xor(ssum1, 16);
        ssum2 += __shfl_xor(ssum2, 8);
        ssum2 += __shfl_xor(ssum2, 16);
        if (act && eslot == 0) {
            float i1 = 1.f / fmaxf(ssum1, 1e-16f);
            float i2 = 1.f / fmaxf(ssum2, 1e-16f);
            float v[16];
#pragma unroll
            for (int j = 0; j < 16; ++j) v[j] = acc1[j] * i1 + acc2[j] * i2;
            unsigned short* op = agg0 + (size_t)dst * 128 + hoff;
            uint4 w0, w1;
            w0.x = pk_bf16(v[0], v[1]);  w0.y = pk_bf16(v[2], v[3]);
            w0.z = pk_bf16(v[4], v[5]);  w0.w = pk_bf16(v[6], v[7]);
            w1.x = pk_bf16(v[8], v[9]);  w1.y = pk_bf16(v[10], v[11]);
            w1.z = pk_bf16(v[12], v[13]); w1.w = pk_bf16(v[14], v[15]);
            *reinterpret_cast<uint4*>(op) = w0;
            *reinterpret_cast<uint4*>(op + 8) = w1;
        }
    } else {
        int dst = (wave - P0) * 2 + (lhb >> 5);
        bool act = dst < N1;
        float qf[16];
        int b1 = 0, n1 = 0;
        if (act) {
            short8v qv0 = *reinterpret_cast<const short8v*>(q1 + (size_t)dst * 128 + hoff);
            short8v qv1 = *reinterpret_cast<const short8v*>(q1 + (size_t)dst * 128 + hoff + 8);
#pragma unroll
            for (int j = 0; j < 8; ++j) {
                qf[j] = bf2f((unsigned short)qv0[j]);
                qf[8 + j] = bf2f((unsigned short)qv1[j]);
            }
            b1 = ipC[dst]; n1 = ipC[dst + 1] - b1;
        } else {
#pragma unroll
            for (int j = 0; j < 16; ++j) qf[j] = 0.f;
        }
        float ps1 = prC[h] * 0.25f * LOG2E;
        float ssum1 = 0.f;
        float acc1[16];
#pragma unroll
        for (int j = 0; j < 16; ++j) acc1[j] = 0.f;
        int it1 = (n1 + 3) >> 2;
        int bat1 = 0;
        uint4 cK1{}, cV1{};
        if (it1 > 0) slot_load(kvC, ssC, b1, n1, 0, lq, lhb, eslot, hoff, bat1, cK1, cV1);
        for (int i = 0; i < it1; ++i) {
            uint4 nK1{}, nV1{};
            if (i + 1 < it1)
                slot_load(kvC, ssC, b1, n1, (i + 1) * 4, lq, lhb, eslot, hoff, bat1, nK1, nV1);
            proc4(cK1, cV1, qf, ps1, (i * 4 + eslot) < n1, ssum1, acc1);
            cK1 = nK1; cV1 = nV1;
        }
#pragma unroll
        for (int j = 0; j < 16; ++j) {
            acc1[j] += __shfl_xor(acc1[j], 8);
            acc1[j] += __shfl_xor(acc1[j], 16);
        }
        ssum1 += __shfl_xor(ssum1, 8);
        ssum1 += __shfl_xor(ssum1, 16);
        if (act && eslot == 0) {
            float i1 = 1.f / fmaxf(ssum1, 1e-16f);
            float v[16];
#pragma unroll
            for (int j = 0; j < 16; ++j) v[j] = acc1[j] * i1;
            unsigned short* op = agg1 + (size_t)dst * 128 + hoff;
            uint4 w0, w1;
            w0.x = pk_bf16(v[0], v[1]);  w0.y = pk_bf16(v[2], v[3]);
            w0.z = pk_bf16(v[4], v[5]);  w0.w = pk_bf16(v[6], v[7]);
            w1.x = pk_bf16(v[8], v[9]);  w1.y = pk_bf16(v[10], v[11]);
            w1.z = pk_bf16(v[12], v[13]); w1.w = pk_bf16(v[14], v[15]);
            *reinterpret_cast<uint4*>(op) = w0;
            *reinterpret_cast<uint4*>(op + 8) = w1;
        }
    }
}

// ============ readout ============
__global__ void colsum_kernel(const unsigned short* __restrict__ h, float* __restrict__ gsum,
                              int M) {
    int c = threadIdx.x;
    float s = 0.f;
    for (int r = blockIdx.x; r < M; r += gridDim.x) s += bf2f(h[(size_t)r * 128 + c]);
    atomicAdd(&gsum[c], s);
}

__global__ void final_kernel(const float* __restrict__ gsum, const float* __restrict__ Wc1,
                             const float* __restrict__ bc1, const float* __restrict__ Wc2,
                             const float* __restrict__ bc2, float* __restrict__ out,
                             float invM) {
    __shared__ float g[128];
    __shared__ float red[128];
    int t = threadIdx.x;
    g[t] = gsum[t] * invM;
    __syncthreads();
    float acc = bc1[t];
    for (int k = 0; k < 128; ++k) acc += g[k] * Wc1[k * 128 + t];
    float zv = fmaxf(acc, 0.f);
    red[t] = zv * Wc2[t];
    __syncthreads();
    for (int off = 64; off > 0; off >>= 1) {
        if (t < off) red[t] += red[t + off];
        __syncthreads();
    }
    if (t == 0) out[0] = 1.f / (1.f + expf(-(red[0] + bc2[0])));
}

extern "C" void kernel_launch(void* const* d_in, const int* in_sizes, int n_in,
                              void* d_out, int out_size, void* d_ws, size_t ws_size,
                              hipStream_t stream) {
    const float* x[2] = {(const float*)d_in[0], (const float*)d_in[1]};
    const int* edges[3] = {(const int*)d_in[2], (const int*)d_in[3], (const int*)d_in[4]};
    const float* Win[2] = {(const float*)d_in[5], (const float*)d_in[7]};
    const float* bin[2] = {(const float*)d_in[6], (const float*)d_in[8]};
    const float* Wk = (const float*)d_in[9];
    const float* bk = (const float*)d_in[10];
    const float* Wq = (const float*)d_in[11];
    const float* bq = (const float*)d_in[12];
    const float* Wv = (const float*)d_in[13];
    const float* bv = (const float*)d_in[14];
    const float* a_rel = (const float*)d_in[15];
    const float* m_rel = (const float*)d_in[16];
    const float* p_rel = (const float*)d_in[17];
    const float* Wa = (const float*)d_in[18];
    const float* ba = (const float*)d_in[19];
    const float* skip = (const float*)d_in[20];
    const float* Wc1 = (const float*)d_in[21];
    const float* bc1 = (const float*)d_in[22];
    const float* Wc2 = (const float*)d_in[23];
    const float* bc2 = (const float*)d_in[24];

    const int N0 = in_sizes[0] / 64;
    const int N1 = in_sizes[1] / 64;
    const int L = in_sizes[9] / (2 * 128 * 128);
    const int Ns[2] = {N0, N1};
    const int RD[3] = {0, 0, 1};
    const int Nmax = (N0 > N1) ? N0 : N1;

    char* p = (char*)d_ws;
    auto alloc = [&](size_t bytes) -> void* {
        void* r = (void*)p;
        p += (bytes + 255) & ~(size_t)255;
        return r;
    };
    unsigned short* h[2];
    unsigned short* q[2];
    unsigned short* agg[2];
    h[0] = (unsigned short*)alloc((size_t)N0 * 128 * 2);
    h[1] = (unsigned short*)alloc((size_t)N1 * 128 * 2);
    q[0] = (unsigned short*)alloc((size_t)N0 * 128 * 2);
    q[1] = (unsigned short*)alloc((size_t)N1 * 128 * 2);
    agg[0] = (unsigned short*)alloc((size_t)N0 * 128 * 2);
    agg[1] = (unsigned short*)alloc((size_t)N1 * 128 * 2);
    unsigned char* kv8[3];
    for (int r = 0; r < 3; ++r) kv8[r] = (unsigned char*)alloc((size_t)Nmax * 256);
    int* indptr[3];
    int* ssrc[3];
    int Er[3];
    for (int r = 0; r < 3; ++r) {
        Er[r] = in_sizes[2 + r] / 2;
        indptr[r] = (int*)alloc((size_t)(Ns[RD[r]] + 1) * 4);
        ssrc[r] = (int*)alloc((size_t)Er[r] * 4);
    }
    unsigned int* pbuf[3];
    for (int r = 0; r < 3; ++r) pbuf[r] = (unsigned int*)alloc((size_t)Er[r] * 4);
    int* cnt3 = (int*)alloc((size_t)3 * Nmax * 4);
    int* texcl3 = (int*)alloc((size_t)3 * Nmax * 4);
    int* bsums3 = (int*)alloc(3 * 64 * 4);
    int* gbkt = (int*)alloc(3 * 65 * 4);
    int* gcur = (int*)alloc(3 * 64 * 4);
    unsigned short* winT = (unsigned short*)alloc(2 * 8192 * 2);
    unsigned short* wqT = (unsigned short*)alloc((size_t)L * 2 * 16384 * 2);
    unsigned short* waT = (unsigned short*)alloc((size_t)L * 2 * 16384 * 2);
    unsigned short* wfT = (unsigned short*)alloc((size_t)L * 6 * 16384 * 2);
    float* bfold = (float*)alloc((size_t)L * 6 * 128 * 4);
    float* gsum = (float*)alloc(128 * 4);

    // ---- weight prep ----
    {
        int nmat = L * 2;
        int convN = 2 * 8192 + 2 * nmat * 16384;
        convT_kernel<<<(convN + 255) / 256, 256, 0, stream>>>(Win[0], Win[1], Wq, Wa, winT, wqT,
                                                              waT, nmat);
        int foldN = L * 6 * 16384 + L * 6 * 128;
        fold_kernel<<<(foldN + 255) / 256, 256, 0, stream>>>(Wk, bk, Wv, bv, a_rel, m_rel, wfT,
                                                             bfold, L);
    }

    // ---- CSR build ----
    {
        Csr3 P;
        int Etot = 0;
        int nbTot = 0;
        for (int r = 0; r < 3; ++r) {
            P.src[r] = edges[r];
            P.dst[r] = edges[r] + Er[r];
            P.E[r] = Er[r];
            P.indptr[r] = indptr[r];
            P.ssrc[r] = ssrc[r];
            P.Nd[r] = Ns[RD[r]];
            P.nb[r] = (P.Nd[r] + 1023) / 1024;
            Etot += Er[r];
            nbTot += P.nb[r];
        }
        P.cnt = cnt3;
        P.texcl = texcl3;
        P.bsums = bsums3;
        P.stride = Nmax;
        if (Nmax <= 65536) {
            hipMemsetAsync(gbkt, 0, 3 * 65 * 4, stream);
            countA_kernel<<<3 * 64, 256, 0, stream>>>(P, gbkt);
            scanG_kernel<<<1, 64, 0, stream>>>(gbkt, gcur);
            partA_kernel<<<3 * PA_BLKS, 256, 0, stream>>>(P, pbuf[0], pbuf[1], pbuf[2], gcur);
            partB2_kernel<<<3 * 64, 256, 0, stream>>>(P, pbuf[0], pbuf[1], pbuf[2], gbkt);
        } else {
            hipMemsetAsync(cnt3, 0, (size_t)3 * Nmax * 4, stream);
            hist3_kernel<<<(Etot + 255) / 256, 256, 0, stream>>>(P, Etot);
            scanA3_kernel<<<nbTot, 1024, 0, stream>>>(P);
            scanB3_kernel<<<3, 64, 0, stream>>>(P);
            scanC3_kernel<<<nbTot, 1024, 0, stream>>>(P);
            scatter3_kernel<<<(Etot + 255) / 256, 256, 0, stream>>>(P, Etot);
        }
    }

    const int nb0 = (N0 + 127) / 128, nb1 = (N1 + 127) / 128;

    // ---- input projection (both types, one dispatch) ----
    gemm_dual<64, 1, 1><<<nb0 + nb1, 256, 0, stream>>>(
        x[0], winT, bin[0], h[0], N0, nullptr, nullptr,
        x[1], winT + 8192, bin[1], h[1], N1, nullptr, nullptr, nb0);

    // ---- layers ----
    for (int l = 0; l < L; ++l) {
        {
            QKVJobs J0{};
            J0.BT[0] = wqT + (size_t)(l * 2 + 0) * 16384;
            J0.bias[0] = bq + (size_t)(l * 2 + 0) * 128;
            J0.outBf[0] = q[0]; J0.outF8[0] = nullptr; J0.f8off[0] = 0;
            int fk0 = (l * 3 + 0) * 2, fk2 = (l * 3 + 2) * 2;
            J0.BT[1] = wfT + (size_t)fk0 * 16384;       J0.bias[1] = bfold + (size_t)fk0 * 128;
            J0.outBf[1] = nullptr; J0.outF8[1] = kv8[0]; J0.f8off[1] = 0;
            J0.BT[2] = wfT + (size_t)(fk0 + 1) * 16384; J0.bias[2] = bfold + (size_t)(fk0 + 1) * 128;
            J0.outBf[2] = nullptr; J0.outF8[2] = kv8[0]; J0.f8off[2] = 128;
            J0.BT[3] = wfT + (size_t)fk2 * 16384;       J0.bias[3] = bfold + (size_t)fk2 * 128;
            J0.outBf[3] = nullptr; J0.outF8[3] = kv8[2]; J0.f8off[3] = 0;
            J0.BT[4] = wfT + (size_t)(fk2 + 1) * 16384; J0.bias[4] = bfold + (size_t)(fk2 + 1) * 128;
            J0.outBf[4] = nullptr; J0.outF8[4] = kv8[2]; J0.f8off[4] = 128;
            QKVJobs J1{};
            J1.BT[0] = wqT + (size_t)(l * 2 + 1) * 16384;
            J1.bias[0] = bq + (size_t)(l * 2 + 1) * 128;
            J1.outBf[0] = q[1]; J1.outF8[0] = nullptr; J1.f8off[0] = 0;
            int fk1 = (l * 3 + 1) * 2;
            J1.BT[1] = wfT + (size_t)fk1 * 16384;       J1.bias[1] = bfold + (size_t)fk1 * 128;
            J1.outBf[1] = nullptr; J1.outF8[1] = kv8[1]; J1.f8off[1] = 0;
            J1.BT[2] = wfT + (size_t)(fk1 + 1) * 16384; J1.bias[2] = bfold + (size_t)(fk1 + 1) * 128;
            J1.outBf[2] = nullptr; J1.outF8[2] = kv8[1]; J1.f8off[2] = 128;
            gemm_qkv2<<<nb0 + nb1, 256, 0, stream>>>(h[0], J0, N0, nb0, h[1], J1, N1);
        }
        // fused attention
        {
            int waves = ((N0 + 1) >> 1) + ((N1 + 1) >> 1);
            attn_fused<<<(waves + 3) / 4, 256, 0, stream>>>(
                q[0], q[1], kv8[0], kv8[1], kv8[2], indptr[0], ssrc[0], indptr[1], ssrc[1],
                indptr[2], ssrc[2], agg[0], agg[1], p_rel + (size_t)(l * 3 + 0) * 8,
                p_rel + (size_t)(l * 3 + 1) * 8, p_rel + (size_t)(l * 3 + 2) * 8, N0, N1);
        }
        // output projection + skip; gelu applied on bf16 A-load
        gemm_dual<128, 2, 0><<<nb0 + nb1, 256, 0, stream>>>(
            agg[0], waT + (size_t)(l * 2 + 0) * 16384, ba + (size_t)(l * 2 + 0) * 128, h[0], N0,
            h[0], skip + (size_t)(l * 2 + 0),
            agg[1], waT + (size_t)(l * 2 + 1) * 16384, ba + (size_t)(l * 2 + 1) * 128, h[1], N1,
            h[1], skip + (size_t)(l * 2 + 1), nb0);
    }

    // ---- readout ----
    hipMemsetAsync(gsum, 0, 128 * 4, stream);
    colsum_kernel<<<512, 128, 0, stream>>>(h[0], gsum, N0);
    final_kernel<<<1, 128, 0, stream>>>(gsum, Wc1, bc1, Wc2, bc2, (float*)d_out,
                                        1.0f / (float)N0);
}

// Round 16
// 477.024 us; speedup vs baseline: 1.0188x; 1.0188x over previous
//
#include <hip/hip_runtime.h>
#include <hip/hip_fp8.h>
#include <math.h>

typedef __attribute__((ext_vector_type(8))) short short8v;   // 8 x bf16 (4 VGPRs)
typedef __attribute__((ext_vector_type(4))) float f32x4;
typedef __attribute__((ext_vector_type(2))) float f32x2;

__device__ __forceinline__ float bf2f(unsigned short u) {
    union { unsigned int i; float f; } x; x.i = ((unsigned int)u) << 16; return x.f;
}
__device__ __forceinline__ unsigned short f2bf(float f) {
    union { float f; unsigned int i; } x; x.f = f;
    unsigned int r = x.i + 0x7fffu + ((x.i >> 16) & 1u);
    return (unsigned short)(r >> 16);
}
// HW packed f32x2 -> 2 x bf16 (v_cvt_pk_bf16_f32, RTNE)
__device__ __forceinline__ unsigned int pk_bf16(float lo, float hi) {
    unsigned int r;
    asm("v_cvt_pk_bf16_f32 %0, %1, %2" : "=v"(r) : "v"(lo), "v"(hi));
    return r;
}
// HW packed 4 x f32 -> 4 x fp8 e4m3 (two v_cvt_pk_fp8_f32)
__device__ __forceinline__ unsigned int pk_fp8x4(float v0, float v1, float v2, float v3) {
    int pk = __builtin_amdgcn_cvt_pk_fp8_f32(v0, v1, 0, false);
    pk = __builtin_amdgcn_cvt_pk_fp8_f32(v2, v3, pk, true);
    return (unsigned int)pk;
}
// tanh-form gelu (~10 ops)
__device__ __forceinline__ float gelu_fast(float x) {
    float y = 0.7978845608f * x * fmaf(0.044715f, x * x, 1.0f);
    y = fminf(fmaxf(y, -9.f), 9.f);
    float u = exp2f(y * 2.8853900817779268f);   // e^{2y}
    float th = 1.f - 2.f * __builtin_amdgcn_rcpf(u + 1.f);
    return 0.5f * x * (1.f + th);
}

// ============ bf16 MFMA GEMM body; B direct from global (L2-hot) ============
template <int K, int MODE, int ASRC>
__device__ __forceinline__ void gemm_body(
    const void* __restrict__ Aptr, const unsigned short* __restrict__ BT,
    const float* __restrict__ bias, unsigned short* __restrict__ Cout, int M,
    const unsigned short* __restrict__ hprev, const float* __restrict__ skipp, int blk) {
    __shared__ short As[128 * K];
    const int tid = threadIdx.x;
    const int row0 = blk * 128;
    const int CH = K / 8;

#pragma unroll
    for (int i = 0; i < (128 * CH) / 256; ++i) {
        int idx = tid + i * 256;
        int r = idx / CH, c = idx % CH;
        int gr = row0 + r;
        if (ASRC == 0) {
            short8v val = {0, 0, 0, 0, 0, 0, 0, 0};
            if (gr < M)
                val = *reinterpret_cast<const short8v*>(
                    (const unsigned short*)Aptr + (size_t)gr * K + c * 8);
            if (MODE == 2) {
                float fv[8];
#pragma unroll
                for (int u = 0; u < 8; ++u) fv[u] = gelu_fast(bf2f((unsigned short)val[u]));
                uint4 uu;
                uu.x = pk_bf16(fv[0], fv[1]);
                uu.y = pk_bf16(fv[2], fv[3]);
                uu.z = pk_bf16(fv[4], fv[5]);
                uu.w = pk_bf16(fv[6], fv[7]);
                *reinterpret_cast<uint4*>((char*)As + r * (2 * K) +
                                          ((c * 16) ^ ((r & 7) << 4))) = uu;
            } else {
                *reinterpret_cast<short8v*>((char*)As + r * (2 * K) +
                                            ((c * 16) ^ ((r & 7) << 4))) = val;
            }
        } else {
            uint4 u = make_uint4(0u, 0u, 0u, 0u);
            if (gr < M) {
                const float* Af = (const float*)Aptr;
                float4 f0 = *reinterpret_cast<const float4*>(Af + (size_t)gr * K + c * 8);
                float4 f1 = *reinterpret_cast<const float4*>(Af + (size_t)gr * K + c * 8 + 4);
                if (MODE == 2) {
                    f0.x = gelu_fast(f0.x); f0.y = gelu_fast(f0.y);
                    f0.z = gelu_fast(f0.z); f0.w = gelu_fast(f0.w);
                    f1.x = gelu_fast(f1.x); f1.y = gelu_fast(f1.y);
                    f1.z = gelu_fast(f1.z); f1.w = gelu_fast(f1.w);
                }
                u.x = pk_bf16(f0.x, f0.y);
                u.y = pk_bf16(f0.z, f0.w);
                u.z = pk_bf16(f1.x, f1.y);
                u.w = pk_bf16(f1.z, f1.w);
            }
            *reinterpret_cast<uint4*>((char*)As + r * (2 * K) + ((c * 16) ^ ((r & 7) << 4))) = u;
        }
    }
    __syncthreads();

    const int lane = tid & 63, wid = tid >> 6;
    const int wr = wid >> 1, wc = wid & 1;
    const int lr = lane & 15, lg = lane >> 4;
    const int swz = (lr & 7) << 4;
    const unsigned short* bbase = BT + (size_t)(wc * 64 + lr) * K + lg * 8;
    f32x4 acc[4][4];
    f32x4 z4 = {0.f, 0.f, 0.f, 0.f};
#pragma unroll
    for (int mi = 0; mi < 4; ++mi)
#pragma unroll
        for (int ni = 0; ni < 4; ++ni) acc[mi][ni] = z4;

#pragma unroll
    for (int ks = 0; ks < K / 32; ++ks) {
        int kc = ks * 64 + lg * 16;
        short8v a[4], b[4];
#pragma unroll
        for (int ni = 0; ni < 4; ++ni)
            b[ni] = *reinterpret_cast<const short8v*>(bbase + (size_t)ni * 16 * K + ks * 32);
#pragma unroll
        for (int mi = 0; mi < 4; ++mi) {
            int r = wr * 64 + mi * 16 + lr;
            a[mi] = *reinterpret_cast<const short8v*>((char*)As + r * (2 * K) + (kc ^ swz));
        }
#pragma unroll
        for (int mi = 0; mi < 4; ++mi)
#pragma unroll
            for (int ni = 0; ni < 4; ++ni)
                acc[mi][ni] =
                    __builtin_amdgcn_mfma_f32_16x16x32_bf16(b[ni], a[mi], acc[mi][ni], 0, 0, 0);
    }

    float beta = 0.f;
    if (MODE == 2) beta = 1.f / (1.f + __expf(-skipp[0]));
#pragma unroll
    for (int mi = 0; mi < 4; ++mi) {
        int gr = row0 + wr * 64 + mi * 16 + lr;
        if (gr >= M) continue;
#pragma unroll
        for (int ni = 0; ni < 4; ++ni) {
            int col0 = wc * 64 + ni * 16 + lg * 4;
            float4 bv = *reinterpret_cast<const float4*>(bias + col0);
            float v0 = acc[mi][ni][0] + bv.x;
            float v1 = acc[mi][ni][1] + bv.y;
            float v2 = acc[mi][ni][2] + bv.z;
            float v3 = acc[mi][ni][3] + bv.w;
            if (MODE == 1) {
                v0 = fmaxf(v0, 0.f); v1 = fmaxf(v1, 0.f);
                v2 = fmaxf(v2, 0.f); v3 = fmaxf(v3, 0.f);
            }
            if (MODE == 2) {
                ushort4 hp = *reinterpret_cast<const ushort4*>(hprev + (size_t)gr * 128 + col0);
                float ob = 1.f - beta;
                v0 = beta * v0 + ob * bf2f(hp.x);
                v1 = beta * v1 + ob * bf2f(hp.y);
                v2 = beta * v2 + ob * bf2f(hp.z);
                v3 = beta * v3 + ob * bf2f(hp.w);
            }
            uint2 us;
            us.x = pk_bf16(v0, v1);
            us.y = pk_bf16(v2, v3);
            *reinterpret_cast<uint2*>(Cout + (size_t)gr * 128 + col0) = us;
        }
    }
}

template <int K, int MODE, int ASRC>
__global__ __launch_bounds__(256) void gemm_dual(
    const void* A0, const unsigned short* BT0, const float* b0, unsigned short* C0, int M0,
    const unsigned short* hp0, const float* sk0,
    const void* A1, const unsigned short* BT1, const float* b1, unsigned short* C1, int M1,
    const unsigned short* hp1, const float* sk1, int nb0) {
    if ((int)blockIdx.x < nb0)
        gemm_body<K, MODE, ASRC>(A0, BT0, b0, C0, M0, hp0, sk0, blockIdx.x);
    else
        gemm_body<K, MODE, ASRC>(A1, BT1, b1, C1, M1, hp1, sk1, blockIdx.x - nb0);
}

// ============ fused QKV GEMM: shared A-tile in LDS, B from global, NB jobs ============
struct QKVJobs {
    const unsigned short* BT[5];
    const float* bias[5];
    unsigned short* outBf[5];
    unsigned char* outF8[5];
    int f8off[5];   // 0 for K, 128 for V
};

template <int NB>
__device__ __forceinline__ void qkv_body(short* __restrict__ As,
                                         const unsigned short* __restrict__ A,
                                         const QKVJobs& J, int M, int blk) {
    const int tid = threadIdx.x;
    const int row0 = blk * 128;

#pragma unroll
    for (int i = 0; i < 8; ++i) {
        int idx = tid + i * 256;
        int r = idx >> 4, c = idx & 15;
        int gr = row0 + r;
        short8v val = {0, 0, 0, 0, 0, 0, 0, 0};
        if (gr < M) val = *reinterpret_cast<const short8v*>(A + (size_t)gr * 128 + c * 8);
        *reinterpret_cast<short8v*>((char*)As + r * 256 + ((c * 16) ^ ((r & 7) << 4))) = val;
    }
    __syncthreads();

    const int lane = tid & 63, wid = tid >> 6;
    const int wr = wid >> 1, wc = wid & 1;
    const int lr = lane & 15, lg = lane >> 4;
    const int swz = (lr & 7) << 4;

    short8v a[4][4];
#pragma unroll
    for (int ks = 0; ks < 4; ++ks) {
        int kc = ks * 64 + lg * 16;
#pragma unroll
        for (int mi = 0; mi < 4; ++mi) {
            int r = wr * 64 + mi * 16 + lr;
            a[ks][mi] = *reinterpret_cast<const short8v*>((char*)As + r * 256 + (kc ^ swz));
        }
    }

#pragma unroll
    for (int m = 0; m < NB; ++m) {
        const unsigned short* bbase = J.BT[m] + (size_t)(wc * 64 + lr) * 128 + lg * 8;
        f32x4 acc[4][4];
        f32x4 z4 = {0.f, 0.f, 0.f, 0.f};
#pragma unroll
        for (int mi = 0; mi < 4; ++mi)
#pragma unroll
            for (int ni = 0; ni < 4; ++ni) acc[mi][ni] = z4;

#pragma unroll
        for (int ks = 0; ks < 4; ++ks) {
            short8v b[4];
#pragma unroll
            for (int ni = 0; ni < 4; ++ni)
                b[ni] = *reinterpret_cast<const short8v*>(bbase + (size_t)ni * 16 * 128 + ks * 32);
#pragma unroll
            for (int mi = 0; mi < 4; ++mi)
#pragma unroll
                for (int ni = 0; ni < 4; ++ni)
                    acc[mi][ni] = __builtin_amdgcn_mfma_f32_16x16x32_bf16(b[ni], a[ks][mi],
                                                                          acc[mi][ni], 0, 0, 0);
        }

        unsigned short* outBf = J.outBf[m];
        unsigned char* outF8 = J.outF8[m];
        int off = J.f8off[m];
        const float* bias = J.bias[m];
#pragma unroll
        for (int mi = 0; mi < 4; ++mi) {
            int gr = row0 + wr * 64 + mi * 16 + lr;
            if (gr >= M) continue;
#pragma unroll
            for (int ni = 0; ni < 4; ++ni) {
                int col0 = wc * 64 + ni * 16 + lg * 4;
                float4 bv = *reinterpret_cast<const float4*>(bias + col0);
                float v0 = acc[mi][ni][0] + bv.x;
                float v1 = acc[mi][ni][1] + bv.y;
                float v2 = acc[mi][ni][2] + bv.z;
                float v3 = acc[mi][ni][3] + bv.w;
                if (outBf) {
                    uint2 us;
                    us.x = pk_bf16(v0, v1);
                    us.y = pk_bf16(v2, v3);
                    *reinterpret_cast<uint2*>(outBf + (size_t)gr * 128 + col0) = us;
                } else {
                    *reinterpret_cast<unsigned int*>(outF8 + (size_t)gr * 256 + off + col0) =
                        pk_fp8x4(v0, v1, v2, v3);
                }
            }
        }
    }
}

__global__ __launch_bounds__(256) void gemm_qkv2(const unsigned short* A0, QKVJobs J0, int M0,
                                                 int nb0, const unsigned short* A1,
                                                 QKVJobs J1, int M1) {
    __shared__ short As[128 * 128];
    if ((int)blockIdx.x < nb0) qkv_body<5>(As, A0, J0, M0, blockIdx.x);
    else qkv_body<3>(As, A1, J1, M1, blockIdx.x - nb0);
}

// ============ weight prep ============
__global__ void convT_kernel(const float* __restrict__ Win0, const float* __restrict__ Win1,
                             const float* __restrict__ Wq, const float* __restrict__ Wa,
                             unsigned short* __restrict__ winT, unsigned short* __restrict__ wqT,
                             unsigned short* __restrict__ waT, int nmat) {
    int gid = blockIdx.x * 256 + threadIdx.x;
    if (gid < 2 * 8192) {
        int m = gid >> 13, idx = gid & 8191;
        int n = idx >> 6, k = idx & 63;
        const float* W = m ? Win1 : Win0;
        winT[gid] = f2bf(W[(size_t)k * 128 + n]);
        return;
    }
    int g = gid - 2 * 8192;
    if (g < nmat * 16384) {
        int mat = g >> 14, idx = g & 16383;
        int n = idx >> 7, k = idx & 127;
        wqT[g] = f2bf(Wq[(size_t)mat * 16384 + (size_t)k * 128 + n]);
        return;
    }
    g -= nmat * 16384;
    if (g < nmat * 16384) {
        int mat = g >> 14, idx = g & 16383;
        int n = idx >> 7, k = idx & 127;
        waT[g] = f2bf(Wa[(size_t)mat * 16384 + (size_t)k * 128 + n]);
    }
}

// ============ relation fold ============
__global__ void fold_kernel(const float* __restrict__ Wk, const float* __restrict__ bk,
                            const float* __restrict__ Wv, const float* __restrict__ bv,
                            const float* __restrict__ a_rel, const float* __restrict__ m_rel,
                            unsigned short* __restrict__ wfT, float* __restrict__ bfold, int L) {
    const int RSarr[3] = {0, 1, 0};
    int gid = blockIdx.x * 256 + threadIdx.x;
    int NW = L * 6 * 16384;
    if (gid < NW) {
        int fold = gid >> 14, idx = gid & 16383;
        int col = idx >> 7, i = idx & 127;
        int kv = fold & 1, lr = fold >> 1, l = lr / 3, r = lr % 3;
        int s = RSarr[r];
        const float* W = (kv ? Wv : Wk) + (size_t)(l * 2 + s) * 16384;
        const float* rel = (kv ? m_rel : a_rel) + (size_t)(l * 3 + r) * 2048;
        int hh = col >> 4, f = col & 15;
        float sacc = 0.f;
#pragma unroll
        for (int d = 0; d < 16; ++d)
            sacc += W[(size_t)i * 128 + hh * 16 + d] * rel[hh * 256 + d * 16 + f];
        wfT[gid] = f2bf(sacc);
        return;
    }
    int g = gid - NW;
    if (g >= L * 6 * 128) return;
    int fold = g >> 7, col = g & 127;
    int kv = fold & 1, lr = fold >> 1, l = lr / 3, r = lr % 3;
    int s = RSarr[r];
    const float* b = (kv ? bv : bk) + (size_t)(l * 2 + s) * 128;
    const float* rel = (kv ? m_rel : a_rel) + (size_t)(l * 3 + r) * 2048;
    int hh = col >> 4, f = col & 15;
    float sacc = 0.f;
#pragma unroll
    for (int d = 0; d < 16; ++d) sacc += b[hh * 16 + d] * rel[hh * 256 + d * 16 + f];
    bfold[fold * 128 + col] = sacc;
}

// ============ CSR build ============
struct Csr3 {
    const int* src[3];
    const int* dst[3];
    int E[3];
    int* cnt;
    int* texcl;
    int* bsums;
    int* indptr[3];
    int* ssrc[3];
    int Nd[3];
    int nb[3];
    int stride;
};

// ---- fallback path (generic N) ----
__global__ void hist3_kernel(Csr3 P, int Etot) {
    int gid = blockIdx.x * 256 + threadIdx.x;
    if (gid >= Etot) return;
    int r = 0, off = gid;
    if (off >= P.E[0]) { off -= P.E[0]; r = 1; if (off >= P.E[1]) { off -= P.E[1]; r = 2; } }
    atomicAdd(&P.cnt[r * P.stride + P.dst[r][off]], 1);
}

__global__ __launch_bounds__(1024) void scanA3_kernel(Csr3 P) {
    __shared__ int s[1024];
    int b = blockIdx.x, r = 0;
    while (b >= P.nb[r]) { b -= P.nb[r]; ++r; }
    const int* cnt = P.cnt + r * P.stride;
    int* texcl = P.texcl + r * P.stride;
    int n = P.Nd[r];
    int t = threadIdx.x;
    int gid = b * 1024 + t;
    int x = (gid < n) ? cnt[gid] : 0;
    s[t] = x;
    __syncthreads();
    for (int off = 1; off < 1024; off <<= 1) {
        int v = (t >= off) ? s[t - off] : 0;
        __syncthreads();
        s[t] += v;
        __syncthreads();
    }
    if (gid < n) texcl[gid] = s[t] - x;
    if (t == 1023) P.bsums[r * 64 + b] = s[1023];
}

__global__ void scanB3_kernel(Csr3 P) {
    int r = blockIdx.x;
    if (threadIdx.x == 0) {
        int run = 0;
        for (int i = 0; i < P.nb[r]; ++i) {
            int t = P.bsums[r * 64 + i];
            P.bsums[r * 64 + i] = run;
            run += t;
        }
    }
}

__global__ __launch_bounds__(1024) void scanC3_kernel(Csr3 P) {
    int b = blockIdx.x, r = 0;
    while (b >= P.nb[r]) { b -= P.nb[r]; ++r; }
    int n = P.Nd[r];
    int gid = b * 1024 + threadIdx.x;
    if (gid < n) {
        int v = P.texcl[r * P.stride + gid] + P.bsums[r * 64 + b];
        P.indptr[r][gid] = v;
        P.cnt[r * P.stride + gid] = v;
    }
    if (gid == 0) P.indptr[r][n] = P.E[r];
}

__global__ void scatter3_kernel(Csr3 P, int Etot) {
    int gid = blockIdx.x * 256 + threadIdx.x;
    if (gid >= Etot) return;
    int r = 0, off = gid;
    if (off >= P.E[0]) { off -= P.E[0]; r = 1; if (off >= P.E[1]) { off -= P.E[1]; r = 2; } }
    int d = P.dst[r][off];
    int p = atomicAdd(&P.cnt[r * P.stride + d], 1);
    P.ssrc[r][p] = P.src[r][off];
}

// ---- fast path (N<=65536): bucket-local CSR ----
#define CA_TILE 4096
__global__ __launch_bounds__(256) void countA_kernel(Csr3 P, int* __restrict__ gbkt) {
    const int r = blockIdx.x >> 6;
    const int blk = blockIdx.x & 63;
    const int tid = threadIdx.x;
    const int* __restrict__ dstp = P.dst[r];
    const int E = P.E[r];
    __shared__ int lc[64];
    for (int t0 = blk * CA_TILE; t0 < E; t0 += 64 * CA_TILE) {
        int cnt = E - t0;
        if (cnt > CA_TILE) cnt = CA_TILE;
        if (tid < 64) lc[tid] = 0;
        __syncthreads();
        for (int i = tid; i < cnt; i += 256) atomicAdd(&lc[dstp[t0 + i] >> 10], 1);
        __syncthreads();
        if (tid < 64 && lc[tid] > 0) atomicAdd(&gbkt[r * 65 + tid], lc[tid]);
        __syncthreads();
    }
}

__global__ void scanG_kernel(int* __restrict__ gbkt, int* __restrict__ gcur) {
    if (threadIdx.x == 0) {
        for (int r = 0; r < 3; ++r) {
            int run = 0;
            for (int b = 0; b < 64; ++b) {
                int t = gbkt[r * 65 + b];
                gbkt[r * 65 + b] = run;
                gcur[r * 64 + b] = run;
                run += t;
            }
            gbkt[r * 65 + 64] = run;
        }
    }
}

#define PA_TILE 4096
#define PA_BLKS 64
__global__ __launch_bounds__(256) void partA_kernel(Csr3 P, unsigned int* __restrict__ pb0,
                                                    unsigned int* __restrict__ pb1,
                                                    unsigned int* __restrict__ pb2,
                                                    int* __restrict__ gcur) {
    unsigned int* pbuf[3] = {pb0, pb1, pb2};
    const int r = blockIdx.x / PA_BLKS;
    const int blk = blockIdx.x % PA_BLKS;
    const int tid = threadIdx.x;
    const int* __restrict__ srcp = P.src[r];
    const int* __restrict__ dstp = P.dst[r];
    const int E = P.E[r];
    unsigned int* __restrict__ out = pbuf[r];
    __shared__ unsigned int stage[PA_TILE];
    __shared__ unsigned char bkt[PA_TILE];
    __shared__ int lcnt[64], lofs[64], lbase[64];

    for (int t0 = blk * PA_TILE; t0 < E; t0 += PA_BLKS * PA_TILE) {
        int cnt = E - t0;
        if (cnt > PA_TILE) cnt = PA_TILE;
        if (tid < 64) lcnt[tid] = 0;
        __syncthreads();
        unsigned int pk[16];
        int lp[16];
#pragma unroll
        for (int j = 0; j < 16; ++j) {
            int i = tid + j * 256;
            if (i < cnt) {
                int s = srcp[t0 + i];
                int d = dstp[t0 + i];
                pk[j] = ((unsigned int)d << 16) | (unsigned int)s;
                lp[j] = atomicAdd(&lcnt[d >> 10], 1);
            }
        }
        __syncthreads();
        if (tid == 0) {
            int run = 0;
            for (int b = 0; b < 64; ++b) { lofs[b] = run; run += lcnt[b]; }
        }
        __syncthreads();
        if (tid < 64 && lcnt[tid] > 0) lbase[tid] = atomicAdd(&gcur[r * 64 + tid], lcnt[tid]);
        __syncthreads();
#pragma unroll
        for (int j = 0; j < 16; ++j) {
            int i = tid + j * 256;
            if (i < cnt) {
                int b = pk[j] >> 26;
                int sp = lofs[b] + lp[j];
                stage[sp] = pk[j];
                bkt[sp] = (unsigned char)b;
            }
        }
        __syncthreads();
        for (int k = tid; k < cnt; k += 256) {
            int b = bkt[k];
            out[lbase[b] + (k - lofs[b])] = stage[k];
        }
        __syncthreads();
    }
}

__global__ __launch_bounds__(256) void partB2_kernel(Csr3 P, const unsigned int* __restrict__ pb0,
                                                     const unsigned int* __restrict__ pb1,
                                                     const unsigned int* __restrict__ pb2,
                                                     const int* __restrict__ gbkt) {
    const unsigned int* pbuf[3] = {pb0, pb1, pb2};
    int r = blockIdx.x >> 6, b = blockIdx.x & 63;
    int Nd = P.Nd[r];
    int nbk = (Nd + 1023) >> 10;
    if (b >= nbk) return;
    int d0 = b << 10;
    int d1 = d0 + 1024;
    if (d1 > Nd) d1 = Nd;
    int lo = gbkt[r * 65 + b];
    int hi = gbkt[r * 65 + b + 1];
    const unsigned int* __restrict__ pin = pbuf[r];
    int* __restrict__ indptr = P.indptr[r];
    int* __restrict__ out = P.ssrc[r];
    const int tid = threadIdx.x;
    __shared__ int cnt[1024];
    __shared__ int exc[1024];
    __shared__ int ps[256];

    for (int i = tid; i < 1024; i += 256) cnt[i] = 0;
    __syncthreads();
    for (int i = lo + tid; i < hi; i += 256)
        atomicAdd(&cnt[(pin[i] >> 16) & 1023], 1);
    __syncthreads();
    int base = tid * 4;
    int s0 = cnt[base], s1 = cnt[base + 1], s2 = cnt[base + 2], s3 = cnt[base + 3];
    int tsum = s0 + s1 + s2 + s3;
    ps[tid] = tsum;
    __syncthreads();
    for (int off = 1; off < 256; off <<= 1) {
        int v = (tid >= off) ? ps[tid - off] : 0;
        __syncthreads();
        ps[tid] += v;
        __syncthreads();
    }
    int texc = ps[tid] - tsum;
    exc[base] = texc;
    exc[base + 1] = texc + s0;
    exc[base + 2] = texc + s0 + s1;
    exc[base + 3] = texc + s0 + s1 + s2;
    __syncthreads();
    for (int i = tid; i < (d1 - d0); i += 256) indptr[d0 + i] = lo + exc[i];
    if (b == nbk - 1 && tid == 0) indptr[Nd] = P.E[r];
    for (int i = tid; i < 1024; i += 256) cnt[i] = exc[i];
    __syncthreads();
    for (int i = lo + tid; i < hi; i += 256) {
        unsigned int pk = pin[i];
        int dl = (pk >> 16) & 1023;
        int p = atomicAdd(&cnt[dl], 1);
        out[lo + p] = (int)(pk & 0xffffu);
    }
}

// ============ attention: head-per-lane, 4 edges/iter, planar fp8 kv, bf16 agg ============
__device__ __forceinline__ void proc4(uint4 Kw, uint4 Vw, const float qf[16], float ps,
                                      bool valid, float& ssum, float acc[16]) {
    float kx[16];
    {
        f32x2 p0 = __builtin_amdgcn_cvt_pk_f32_fp8(Kw.x, false);
        f32x2 p1 = __builtin_amdgcn_cvt_pk_f32_fp8(Kw.x, true);
        f32x2 p2 = __builtin_amdgcn_cvt_pk_f32_fp8(Kw.y, false);
        f32x2 p3 = __builtin_amdgcn_cvt_pk_f32_fp8(Kw.y, true);
        f32x2 p4 = __builtin_amdgcn_cvt_pk_f32_fp8(Kw.z, false);
        f32x2 p5 = __builtin_amdgcn_cvt_pk_f32_fp8(Kw.z, true);
        f32x2 p6 = __builtin_amdgcn_cvt_pk_f32_fp8(Kw.w, false);
        f32x2 p7 = __builtin_amdgcn_cvt_pk_f32_fp8(Kw.w, true);
        kx[0] = p0[0]; kx[1] = p0[1]; kx[2] = p1[0]; kx[3] = p1[1];
        kx[4] = p2[0]; kx[5] = p2[1]; kx[6] = p3[0]; kx[7] = p3[1];
        kx[8] = p4[0]; kx[9] = p4[1]; kx[10] = p5[0]; kx[11] = p5[1];
        kx[12] = p6[0]; kx[13] = p6[1]; kx[14] = p7[0]; kx[15] = p7[1];
    }
    float t = 0.f;
#pragma unroll
    for (int j = 0; j < 16; ++j) t = fmaf(qf[j], kx[j], t);
    float e = fminf(fmaxf(t * ps, -40.f), 40.f);
    float w = valid ? exp2f(e) : 0.f;
    ssum += w;
    float vx[16];
    {
        f32x2 p0 = __builtin_amdgcn_cvt_pk_f32_fp8(Vw.x, false);
        f32x2 p1 = __builtin_amdgcn_cvt_pk_f32_fp8(Vw.x, true);
        f32x2 p2 = __builtin_amdgcn_cvt_pk_f32_fp8(Vw.y, false);
        f32x2 p3 = __builtin_amdgcn_cvt_pk_f32_fp8(Vw.y, true);
        f32x2 p4 = __builtin_amdgcn_cvt_pk_f32_fp8(Vw.z, false);
        f32x2 p5 = __builtin_amdgcn_cvt_pk_f32_fp8(Vw.z, true);
        f32x2 p6 = __builtin_amdgcn_cvt_pk_f32_fp8(Vw.w, false);
        f32x2 p7 = __builtin_amdgcn_cvt_pk_f32_fp8(Vw.w, true);
        vx[0] = p0[0]; vx[1] = p0[1]; vx[2] = p1[0]; vx[3] = p1[1];
        vx[4] = p2[0]; vx[5] = p2[1]; vx[6] = p3[0]; vx[7] = p3[1];
        vx[8] = p4[0]; vx[9] = p4[1]; vx[10] = p5[0]; vx[11] = p5[1];
        vx[12] = p6[0]; vx[13] = p6[1]; vx[14] = p7[0]; vx[15] = p7[1];
    }
#pragma unroll
    for (int j = 0; j < 16; ++j) acc[j] = fmaf(w, vx[j], acc[j]);
}

__device__ __forceinline__ void slot_load(const unsigned char* __restrict__ kv,
                                          const int* __restrict__ ss, int beg, int n, int j4,
                                          int lq, int lhb, int eslot, int hoff, int& bat,
                                          uint4& Kw, uint4& Vw) {
    if ((j4 & 31) == 0) bat = (j4 + lq < n) ? ss[beg + j4 + lq] : 0;
    int s = __shfl(bat, lhb + ((j4 + eslot) & 31));
    const unsigned char* bp = kv + (size_t)s * 256 + hoff;
    Kw = *reinterpret_cast<const uint4*>(bp);
    Vw = *reinterpret_cast<const uint4*>(bp + 128);
}

__global__ __launch_bounds__(256) void attn_fused(
    const unsigned short* __restrict__ q0, const unsigned short* __restrict__ q1,
    const unsigned char* __restrict__ kvA, const unsigned char* __restrict__ kvB,
    const unsigned char* __restrict__ kvC,
    const int* __restrict__ ipA, const int* __restrict__ ssA,
    const int* __restrict__ ipB, const int* __restrict__ ssB,
    const int* __restrict__ ipC, const int* __restrict__ ssC,
    unsigned short* __restrict__ agg0, unsigned short* __restrict__ agg1,
    const float* __restrict__ prA, const float* __restrict__ prB,
    const float* __restrict__ prC, int N0, int N1) {
    const int wave = (blockIdx.x * blockDim.x + threadIdx.x) >> 6;
    const int lane = threadIdx.x & 63;
    const int lq = lane & 31;
    const int lhb = lane & 32;
    const int h = lq & 7;
    const int eslot = lq >> 3;
    const int hoff = h * 16;
    const float LOG2E = 1.4426950408889634f;
    const int P0 = (N0 + 1) >> 1;
    const int P1 = (N1 + 1) >> 1;
    if (wave >= P0 + P1) return;

    if (wave < P0) {
        int dst = wave * 2 + (lhb >> 5);
        bool act = dst < N0;
        float qf[16];
        int b1 = 0, n1 = 0, b2 = 0, n2 = 0;
        if (act) {
            short8v qv0 = *reinterpret_cast<const short8v*>(q0 + (size_t)dst * 128 + hoff);
            short8v qv1 = *reinterpret_cast<const short8v*>(q0 + (size_t)dst * 128 + hoff + 8);
#pragma unroll
            for (int j = 0; j < 8; ++j) {
                qf[j] = bf2f((unsigned short)qv0[j]);
                qf[8 + j] = bf2f((unsigned short)qv1[j]);
            }
            b1 = ipA[dst]; n1 = ipA[dst + 1] - b1;
            b2 = ipB[dst]; n2 = ipB[dst + 1] - b2;
        } else {
#pragma unroll
            for (int j = 0; j < 16; ++j) qf[j] = 0.f;
        }
        float ps1 = prA[h] * 0.25f * LOG2E;
        float ps2 = prB[h] * 0.25f * LOG2E;
        float ssum1 = 0.f, ssum2 = 0.f;
        float acc1[16], acc2[16];
#pragma unroll
        for (int j = 0; j < 16; ++j) { acc1[j] = 0.f; acc2[j] = 0.f; }
        int it1 = (n1 + 3) >> 2, it2 = (n2 + 3) >> 2;
        int itm = (it1 > it2) ? it1 : it2;
        int bat1 = 0, bat2 = 0;
        uint4 cK1{}, cV1{}, cK2{}, cV2{};
        if (it1 > 0) slot_load(kvA, ssA, b1, n1, 0, lq, lhb, eslot, hoff, bat1, cK1, cV1);
        if (it2 > 0) slot_load(kvB, ssB, b2, n2, 0, lq, lhb, eslot, hoff, bat2, cK2, cV2);
        for (int i = 0; i < itm; ++i) {
            uint4 nK1{}, nV1{}, nK2{}, nV2{};
            if (i + 1 < it1)
                slot_load(kvA, ssA, b1, n1, (i + 1) * 4, lq, lhb, eslot, hoff, bat1, nK1, nV1);
            if (i + 1 < it2)
                slot_load(kvB, ssB, b2, n2, (i + 1) * 4, lq, lhb, eslot, hoff, bat2, nK2, nV2);
            if (i < it1) proc4(cK1, cV1, qf, ps1, (i * 4 + eslot) < n1, ssum1, acc1);
            if (i < it2) proc4(cK2, cV2, qf, ps2, (i * 4 + eslot) < n2, ssum2, acc2);
            cK1 = nK1; cV1 = nV1; cK2 = nK2; cV2 = nV2;
        }
#pragma unroll
        for (int j = 0; j < 16; ++j) {
            acc1[j] += __shfl_xor(acc1[j], 8);
            acc1[j] += __shfl_xor(acc1[j], 16);
            acc2[j] += __shfl_xor(acc2[j], 8);
            acc2[j] += __shfl_xor(acc2[j], 16);
        }
        ssum1 += __shfl_xor(ssum1, 8);
        ssum1 += __shfl_xor(ssum1, 16);
        ssum2 += __shfl_xor(ssum2, 8);
        ssum2 += __shfl_xor(ssum2, 16);
        if (act && eslot == 0) {
            float i1 = 1.f / fmaxf(ssum1, 1e-16f);
            float i2 = 1.f / fmaxf(ssum2, 1e-16f);
            float v[16];
#pragma unroll
            for (int j = 0; j < 16; ++j) v[j] = acc1[j] * i1 + acc2[j] * i2;
            unsigned short* op = agg0 + (size_t)dst * 128 + hoff;
            uint4 w0, w1;
            w0.x = pk_bf16(v[0], v[1]);  w0.y = pk_bf16(v[2], v[3]);
            w0.z = pk_bf16(v[4], v[5]);  w0.w = pk_bf16(v[6], v[7]);
            w1.x = pk_bf16(v[8], v[9]);  w1.y = pk_bf16(v[10], v[11]);
            w1.z = pk_bf16(v[12], v[13]); w1.w = pk_bf16(v[14], v[15]);
            *reinterpret_cast<uint4*>(op) = w0;
            *reinterpret_cast<uint4*>(op + 8) = w1;
        }
    } else {
        int dst = (wave - P0) * 2 + (lhb >> 5);
        bool act = dst < N1;
        float qf[16];
        int b1 = 0, n1 = 0;
        if (act) {
            short8v qv0 = *reinterpret_cast<const short8v*>(q1 + (size_t)dst * 128 + hoff);
            short8v qv1 = *reinterpret_cast<const short8v*>(q1 + (size_t)dst * 128 + hoff + 8);
#pragma unroll
            for (int j = 0; j < 8; ++j) {
                qf[j] = bf2f((unsigned short)qv0[j]);
                qf[8 + j] = bf2f((unsigned short)qv1[j]);
            }
            b1 = ipC[dst]; n1 = ipC[dst + 1] - b1;
        } else {
#pragma unroll
            for (int j = 0; j < 16; ++j) qf[j] = 0.f;
        }
        float ps1 = prC[h] * 0.25f * LOG2E;
        float ssum1 = 0.f;
        float acc1[16];
#pragma unroll
        for (int j = 0; j < 16; ++j) acc1[j] = 0.f;
        int it1 = (n1 + 3) >> 2;
        int bat1 = 0;
        uint4 cK1{}, cV1{};
        if (it1 > 0) slot_load(kvC, ssC, b1, n1, 0, lq, lhb, eslot, hoff, bat1, cK1, cV1);
        for (int i = 0; i < it1; ++i) {
            uint4 nK1{}, nV1{};
            if (i + 1 < it1)
                slot_load(kvC, ssC, b1, n1, (i + 1) * 4, lq, lhb, eslot, hoff, bat1, nK1, nV1);
            proc4(cK1, cV1, qf, ps1, (i * 4 + eslot) < n1, ssum1, acc1);
            cK1 = nK1; cV1 = nV1;
        }
#pragma unroll
        for (int j = 0; j < 16; ++j) {
            acc1[j] += __shfl_xor(acc1[j], 8);
            acc1[j] += __shfl_xor(acc1[j], 16);
        }
        ssum1 += __shfl_xor(ssum1, 8);
        ssum1 += __shfl_xor(ssum1, 16);
        if (act && eslot == 0) {
            float i1 = 1.f / fmaxf(ssum1, 1e-16f);
            float v[16];
#pragma unroll
            for (int j = 0; j < 16; ++j) v[j] = acc1[j] * i1;
            unsigned short* op = agg1 + (size_t)dst * 128 + hoff;
            uint4 w0, w1;
            w0.x = pk_bf16(v[0], v[1]);  w0.y = pk_bf16(v[2], v[3]);
            w0.z = pk_bf16(v[4], v[5]);  w0.w = pk_bf16(v[6], v[7]);
            w1.x = pk_bf16(v[8], v[9]);  w1.y = pk_bf16(v[10], v[11]);
            w1.z = pk_bf16(v[12], v[13]); w1.w = pk_bf16(v[14], v[15]);
            *reinterpret_cast<uint4*>(op) = w0;
            *reinterpret_cast<uint4*>(op + 8) = w1;
        }
    }
}

// ============ readout ============
__global__ void colsum_kernel(const unsigned short* __restrict__ h, float* __restrict__ gsum,
                              int M) {
    int c = threadIdx.x;
    float s = 0.f;
    for (int r = blockIdx.x; r < M; r += gridDim.x) s += bf2f(h[(size_t)r * 128 + c]);
    atomicAdd(&gsum[c], s);
}

__global__ void final_kernel(const float* __restrict__ gsum, const float* __restrict__ Wc1,
                             const float* __restrict__ bc1, const float* __restrict__ Wc2,
                             const float* __restrict__ bc2, float* __restrict__ out,
                             float invM) {
    __shared__ float g[128];
    __shared__ float red[128];
    int t = threadIdx.x;
    g[t] = gsum[t] * invM;
    __syncthreads();
    float acc = bc1[t];
    for (int k = 0; k < 128; ++k) acc += g[k] * Wc1[k * 128 + t];
    float zv = fmaxf(acc, 0.f);
    red[t] = zv * Wc2[t];
    __syncthreads();
    for (int off = 64; off > 0; off >>= 1) {
        if (t < off) red[t] += red[t + off];
        __syncthreads();
    }
    if (t == 0) out[0] = 1.f / (1.f + expf(-(red[0] + bc2[0])));
}

extern "C" void kernel_launch(void* const* d_in, const int* in_sizes, int n_in,
                              void* d_out, int out_size, void* d_ws, size_t ws_size,
                              hipStream_t stream) {
    const float* x[2] = {(const float*)d_in[0], (const float*)d_in[1]};
    const int* edges[3] = {(const int*)d_in[2], (const int*)d_in[3], (const int*)d_in[4]};
    const float* Win[2] = {(const float*)d_in[5], (const float*)d_in[7]};
    const float* bin[2] = {(const float*)d_in[6], (const float*)d_in[8]};
    const float* Wk = (const float*)d_in[9];
    const float* bk = (const float*)d_in[10];
    const float* Wq = (const float*)d_in[11];
    const float* bq = (const float*)d_in[12];
    const float* Wv = (const float*)d_in[13];
    const float* bv = (const float*)d_in[14];
    const float* a_rel = (const float*)d_in[15];
    const float* m_rel = (const float*)d_in[16];
    const float* p_rel = (const float*)d_in[17];
    const float* Wa = (const float*)d_in[18];
    const float* ba = (const float*)d_in[19];
    const float* skip = (const float*)d_in[20];
    const float* Wc1 = (const float*)d_in[21];
    const float* bc1 = (const float*)d_in[22];
    const float* Wc2 = (const float*)d_in[23];
    const float* bc2 = (const float*)d_in[24];

    const int N0 = in_sizes[0] / 64;
    const int N1 = in_sizes[1] / 64;
    const int L = in_sizes[9] / (2 * 128 * 128);
    const int Ns[2] = {N0, N1};
    const int RD[3] = {0, 0, 1};
    const int Nmax = (N0 > N1) ? N0 : N1;

    char* p = (char*)d_ws;
    auto alloc = [&](size_t bytes) -> void* {
        void* r = (void*)p;
        p += (bytes + 255) & ~(size_t)255;
        return r;
    };
    unsigned short* h[2];
    unsigned short* q[2];
    unsigned short* agg[2];
    h[0] = (unsigned short*)alloc((size_t)N0 * 128 * 2);
    h[1] = (unsigned short*)alloc((size_t)N1 * 128 * 2);
    q[0] = (unsigned short*)alloc((size_t)N0 * 128 * 2);
    q[1] = (unsigned short*)alloc((size_t)N1 * 128 * 2);
    agg[0] = (unsigned short*)alloc((size_t)N0 * 128 * 2);
    agg[1] = (unsigned short*)alloc((size_t)N1 * 128 * 2);
    unsigned char* kv8[3];
    for (int r = 0; r < 3; ++r) kv8[r] = (unsigned char*)alloc((size_t)Nmax * 256);
    int* indptr[3];
    int* ssrc[3];
    int Er[3];
    for (int r = 0; r < 3; ++r) {
        Er[r] = in_sizes[2 + r] / 2;
        indptr[r] = (int*)alloc((size_t)(Ns[RD[r]] + 1) * 4);
        ssrc[r] = (int*)alloc((size_t)Er[r] * 4);
    }
    unsigned int* pbuf[3];
    for (int r = 0; r < 3; ++r) pbuf[r] = (unsigned int*)alloc((size_t)Er[r] * 4);
    int* cnt3 = (int*)alloc((size_t)3 * Nmax * 4);
    int* texcl3 = (int*)alloc((size_t)3 * Nmax * 4);
    int* bsums3 = (int*)alloc(3 * 64 * 4);
    int* gbkt = (int*)alloc(3 * 65 * 4);
    int* gcur = (int*)alloc(3 * 64 * 4);
    unsigned short* winT = (unsigned short*)alloc(2 * 8192 * 2);
    unsigned short* wqT = (unsigned short*)alloc((size_t)L * 2 * 16384 * 2);
    unsigned short* waT = (unsigned short*)alloc((size_t)L * 2 * 16384 * 2);
    unsigned short* wfT = (unsigned short*)alloc((size_t)L * 6 * 16384 * 2);
    float* bfold = (float*)alloc((size_t)L * 6 * 128 * 4);
    float* gsum = (float*)alloc(128 * 4);

    // ---- weight prep ----
    {
        int nmat = L * 2;
        int convN = 2 * 8192 + 2 * nmat * 16384;
        convT_kernel<<<(convN + 255) / 256, 256, 0, stream>>>(Win[0], Win[1], Wq, Wa, winT, wqT,
                                                              waT, nmat);
        int foldN = L * 6 * 16384 + L * 6 * 128;
        fold_kernel<<<(foldN + 255) / 256, 256, 0, stream>>>(Wk, bk, Wv, bv, a_rel, m_rel, wfT,
                                                             bfold, L);
    }

    // ---- CSR build ----
    {
        Csr3 P;
        int Etot = 0;
        int nbTot = 0;
        for (int r = 0; r < 3; ++r) {
            P.src[r] = edges[r];
            P.dst[r] = edges[r] + Er[r];
            P.E[r] = Er[r];
            P.indptr[r] = indptr[r];
            P.ssrc[r] = ssrc[r];
            P.Nd[r] = Ns[RD[r]];
            P.nb[r] = (P.Nd[r] + 1023) / 1024;
            Etot += Er[r];
            nbTot += P.nb[r];
        }
        P.cnt = cnt3;
        P.texcl = texcl3;
        P.bsums = bsums3;
        P.stride = Nmax;
        if (Nmax <= 65536) {
            hipMemsetAsync(gbkt, 0, 3 * 65 * 4, stream);
            countA_kernel<<<3 * 64, 256, 0, stream>>>(P, gbkt);
            scanG_kernel<<<1, 64, 0, stream>>>(gbkt, gcur);
            partA_kernel<<<3 * PA_BLKS, 256, 0, stream>>>(P, pbuf[0], pbuf[1], pbuf[2], gcur);
            partB2_kernel<<<3 * 64, 256, 0, stream>>>(P, pbuf[0], pbuf[1], pbuf[2], gbkt);
        } else {
            hipMemsetAsync(cnt3, 0, (size_t)3 * Nmax * 4, stream);
            hist3_kernel<<<(Etot + 255) / 256, 256, 0, stream>>>(P, Etot);
            scanA3_kernel<<<nbTot, 1024, 0, stream>>>(P);
            scanB3_kernel<<<3, 64, 0, stream>>>(P);
            scanC3_kernel<<<nbTot, 1024, 0, stream>>>(P);
            scatter3_kernel<<<(Etot + 255) / 256, 256, 0, stream>>>(P, Etot);
        }
    }

    const int nb0 = (N0 + 127) / 128, nb1 = (N1 + 127) / 128;

    // ---- input projection (both types, one dispatch) ----
    gemm_dual<64, 1, 1><<<nb0 + nb1, 256, 0, stream>>>(
        x[0], winT, bin[0], h[0], N0, nullptr, nullptr,
        x[1], winT + 8192, bin[1], h[1], N1, nullptr, nullptr, nb0);

    // ---- layers ----
    for (int l = 0; l < L; ++l) {
        {
            QKVJobs J0{};
            J0.BT[0] = wqT + (size_t)(l * 2 + 0) * 16384;
            J0.bias[0] = bq + (size_t)(l * 2 + 0) * 128;
            J0.outBf[0] = q[0]; J0.outF8[0] = nullptr; J0.f8off[0] = 0;
            int fk0 = (l * 3 + 0) * 2, fk2 = (l * 3 + 2) * 2;
            J0.BT[1] = wfT + (size_t)fk0 * 16384;       J0.bias[1] = bfold + (size_t)fk0 * 128;
            J0.outBf[1] = nullptr; J0.outF8[1] = kv8[0]; J0.f8off[1] = 0;
            J0.BT[2] = wfT + (size_t)(fk0 + 1) * 16384; J0.bias[2] = bfold + (size_t)(fk0 + 1) * 128;
            J0.outBf[2] = nullptr; J0.outF8[2] = kv8[0]; J0.f8off[2] = 128;
            J0.BT[3] = wfT + (size_t)fk2 * 16384;       J0.bias[3] = bfold + (size_t)fk2 * 128;
            J0.outBf[3] = nullptr; J0.outF8[3] = kv8[2]; J0.f8off[3] = 0;
            J0.BT[4] = wfT + (size_t)(fk2 + 1) * 16384; J0.bias[4] = bfold + (size_t)(fk2 + 1) * 128;
            J0.outBf[4] = nullptr; J0.outF8[4] = kv8[2]; J0.f8off[4] = 128;
            QKVJobs J1{};
            J1.BT[0] = wqT + (size_t)(l * 2 + 1) * 16384;
            J1.bias[0] = bq + (size_t)(l * 2 + 1) * 128;
            J1.outBf[0] = q[1]; J1.outF8[0] = nullptr; J1.f8off[0] = 0;
            int fk1 = (l * 3 + 1) * 2;
            J1.BT[1] = wfT + (size_t)fk1 * 16384;       J1.bias[1] = bfold + (size_t)fk1 * 128;
            J1.outBf[1] = nullptr; J1.outF8[1] = kv8[1]; J1.f8off[1] = 0;
            J1.BT[2] = wfT + (size_t)(fk1 + 1) * 16384; J1.bias[2] = bfold + (size_t)(fk1 + 1) * 128;
            J1.outBf[2] = nullptr; J1.outF8[2] = kv8[1]; J1.f8off[2] = 128;
            gemm_qkv2<<<nb0 + nb1, 256, 0, stream>>>(h[0], J0, N0, nb0, h[1], J1, N1);
        }
        // fused attention
        {
            int waves = ((N0 + 1) >> 1) + ((N1 + 1) >> 1);
            attn_fused<<<(waves + 3) / 4, 256, 0, stream>>>(
                q[0], q[1], kv8[0], kv8[1], kv8[2], indptr[0], ssrc[0], indptr[1], ssrc[1],
                indptr[2], ssrc[2], agg[0], agg[1], p_rel + (size_t)(l * 3 + 0) * 8,
                p_rel + (size_t)(l * 3 + 1) * 8, p_rel + (size_t)(l * 3 + 2) * 8, N0, N1);
        }
        // output projection + skip; gelu applied on bf16 A-load
        gemm_dual<128, 2, 0><<<nb0 + nb1, 256, 0, stream>>>(
            agg[0], waT + (size_t)(l * 2 + 0) * 16384, ba + (size_t)(l * 2 + 0) * 128, h[0], N0,
            h[0], skip + (size_t)(l * 2 + 0),
            agg[1], waT + (size_t)(l * 2 + 1) * 16384, ba + (size_t)(l * 2 + 1) * 128, h[1], N1,
            h[1], skip + (size_t)(l * 2 + 1), nb0);
    }

    // ---- readout ----
    hipMemsetAsync(gsum, 0, 128 * 4, stream);
    colsum_kernel<<<512, 128, 0, stream>>>(h[0], gsum, N0);
    final_kernel<<<1, 128, 0, stream>>>(gsum, Wc1, bc1, Wc2, bc2, (float*)d_out,
                                        1.0f / (float)N0);
}